// Round 8
// baseline (126.023 us; speedup 1.0000x reference)
//
#include <hip/hip_runtime.h>
#include <hip/hip_bf16.h>
#include <stdint.h>
#include <stddef.h>

#define NTOT 8192
#define BS   4096
#define DIM  1024
#define NT2  1056   // rect-triangular blocks: sum over pair-rows P of 2*(32-P)

// ws layout (bytes)
#define OFF_TB      0u          // bf16 total: 8192*1024*2 = 16777216
#define OFF_SQ      16777216u   // f32 [8192]
#define OFF_COLPART 16809984u   // f32 [128][1024]
#define OFF_BWP     17334272u   // f32 [8]
#define OFF_PART    17334336u   // f32 [NT2]

typedef __attribute__((ext_vector_type(8))) short bf16x8;
typedef __attribute__((ext_vector_type(4))) float f32x4;

__device__ __forceinline__ unsigned short f2bf_rne(float f) {
  unsigned u = __float_as_uint(f);
  u += 0x7fffu + ((u >> 16) & 1u);
  return (unsigned short)(u >> 16);
}

__device__ __forceinline__ float bf2f(unsigned short h) {
  return __uint_as_float((unsigned)h << 16);
}

__device__ __forceinline__ float fast_sqrt(float x) {
#if __has_builtin(__builtin_amdgcn_sqrtf)
  return __builtin_amdgcn_sqrtf(x);
#else
  float r; asm("v_sqrt_f32 %0, %1" : "=v"(r) : "v"(x)); return r;
#endif
}

__device__ __forceinline__ float fast_exp2(float x) {
#if __has_builtin(__builtin_amdgcn_exp2f)
  return __builtin_amdgcn_exp2f(x);
#else
  float r; asm("v_exp_f32 %0, %1" : "=v"(r) : "v"(x)); return r;
#endif
}

__device__ __forceinline__ void load_lds16(const void* g, void* l) {
  __builtin_amdgcn_global_load_lds((const __attribute__((address_space(1))) void*)g,
                                   (__attribute__((address_space(3))) void*)l,
                                   16, 0, 0);
}

// ---- kernel A: bf16 convert + row sums of squares (16 rows/block) ----
__global__ __launch_bounds__(256) void prep_kernel(const float* __restrict__ src,
                                                   const float* __restrict__ tgt,
                                                   unsigned short* __restrict__ tb,
                                                   float* __restrict__ sq) {
  const int t = threadIdx.x;
  const int lane = t & 63, wave = t >> 6;
  const int r0 = blockIdx.x * 16;
  __shared__ float rs[16][4];
#pragma unroll 4
  for (int r = 0; r < 16; ++r) {
    const int row = r0 + r;
    const float* base = (row < BS) ? (src + (size_t)row * DIM)
                                   : (tgt + (size_t)(row - BS) * DIM);
    float4 v = *reinterpret_cast<const float4*>(base + t * 4);
    ushort4 b;
    b.x = f2bf_rne(v.x); b.y = f2bf_rne(v.y);
    b.z = f2bf_rne(v.z); b.w = f2bf_rne(v.w);
    *reinterpret_cast<ushort4*>(tb + (size_t)row * DIM + t * 4) = b;
    float s = v.x*v.x + v.y*v.y + v.z*v.z + v.w*v.w;
#pragma unroll
    for (int off = 32; off > 0; off >>= 1) s += __shfl_down(s, off, 64);
    if (lane == 0) rs[r][wave] = s;
  }
  __syncthreads();
  if (t < 16) sq[r0 + t] = (rs[t][0] + rs[t][1]) + (rs[t][2] + rs[t][3]);
}

// ---- kernel B: column-sum partials from the cache-hot bf16 copy ----
__global__ __launch_bounds__(256) void colsum_kernel(const unsigned short* __restrict__ tb,
                                                     float* __restrict__ colpart) {
  const int g = blockIdx.x;   // 128 blocks, 64 rows each
  const int t = threadIdx.x;  // 4 cols per thread
  float a0 = 0.f, a1 = 0.f, a2 = 0.f, a3 = 0.f;
  for (int r = 0; r < 64; ++r) {
    const int row = g * 64 + r;
    ushort4 u = *reinterpret_cast<const ushort4*>(tb + (size_t)row * DIM + t * 4);
    a0 += bf2f(u.x); a1 += bf2f(u.y); a2 += bf2f(u.z); a3 += bf2f(u.w);
  }
  float4 o = {a0, a1, a2, a3};
  *reinterpret_cast<float4*>(colpart + (size_t)g * 1024 + t * 4) = o;
}

// ---- kernel C: bandwidth from analytic sum(L2), 1024 threads (1 col/thread) ----
__global__ __launch_bounds__(1024) void bw_kernel(const float* __restrict__ sq,
                                                  const float* __restrict__ colpart,
                                                  float* __restrict__ bwp) {
  const int t = threadIdx.x;
  double s1 = 0.0;
#pragma unroll
  for (int i = 0; i < 8; ++i) s1 += (double)sq[t + i * 1024];
  float s = 0.f;
  for (int g = 0; g < 128; ++g) s += colpart[(size_t)g * 1024 + t];
  double s2 = (double)s * (double)s;
  __shared__ double r1[1024], r2[1024];
  r1[t] = s1; r2[t] = s2;
  __syncthreads();
  for (int off = 512; off > 0; off >>= 1) {
    if (t < off) { r1[t] += r1[t + off]; r2[t] += r2[t + off]; }
    __syncthreads();
  }
  if (t == 0) {
    const double n = (double)NTOT;
    double sumL2 = 2.0 * n * r1[0] - 2.0 * r2[0];
    double bw = sumL2 / (n * n - n);
    bw = bw / 4.0;  // KERNEL_MUL^(KERNEL_NUM//2) = 2^2
    const double LOG2E = 1.4426950408889634;
    for (int k = 0; k < 5; ++k)
      bwp[k] = (float)(-LOG2E / (bw * (double)(1 << k)));  // exp2-folded
  }
}

// Pair-interleaved LDS layout (BK=32, rows of 64B): two rows share a 128B line
// of 8 16B-slots. Chunk f: line=f>>3, slot=f&7, s'=slot^(line&7),
// row=2*line+(s'>>2), kchunk=s'&3.  Read(row,kg): slot=(kg+4*(row&1))^((row>>1)&7).
// 16 lanes at fixed kg cover all 8 slots exactly twice -> 2-way alias (free).
// gload_lds dest stays linear; the source address carries the inverse swizzle.

// stage one K=32 tile pair: A 512 chunks (2/thread) + B 1024 chunks (4/thread)
#define STAGE6(k0, ldsA, ldsB)                                                   \
  do {                                                                           \
    load_lds16(T + goff[0] + (k0), (ldsA) + (size_t)(0 * 256 + wave * 64) * 8);  \
    load_lds16(T + goff[1] + (k0), (ldsA) + (size_t)(1 * 256 + wave * 64) * 8);  \
    load_lds16(T + goff[2] + (k0), (ldsB) + (size_t)(0 * 256 + wave * 64) * 8);  \
    load_lds16(T + goff[3] + (k0), (ldsB) + (size_t)(1 * 256 + wave * 64) * 8);  \
    load_lds16(T + goff[4] + (k0), (ldsB) + (size_t)(2 * 256 + wave * 64) * 8);  \
    load_lds16(T + goff[5] + (k0), (ldsB) + (size_t)(3 * 256 + wave * 64) * 8);  \
  } while (0)

// one K=32 step: wave computes 128x64 via a[8] x b[4] -> 32 MFMA, 12 ds_read_b128
#define COMPUTE32(Abuf, Bbuf)                                                    \
  do {                                                                           \
    bf16x8 a[8], b[4];                                                           \
    _Pragma("unroll")                                                            \
    for (int m = 0; m < 8; ++m)                                                  \
      a[m] = *reinterpret_cast<const bf16x8*>(&(Abuf)[aoffl[m]]);                \
    _Pragma("unroll")                                                            \
    for (int n = 0; n < 4; ++n)                                                  \
      b[n] = *reinterpret_cast<const bf16x8*>(&(Bbuf)[boffl[n]]);                \
    __builtin_amdgcn_s_setprio(1);                                               \
    _Pragma("unroll")                                                            \
    for (int m = 0; m < 8; ++m)                                                  \
      _Pragma("unroll")                                                          \
      for (int n = 0; n < 4; ++n)                                                \
        acc[m][n] = __builtin_amdgcn_mfma_f32_16x16x32_bf16(a[m], b[n],          \
                                                            acc[m][n], 0, 0, 0); \
    __builtin_amdgcn_s_setprio(0);                                               \
  } while (0)

// ---- kernel D: fused bf16 Gram GEMM + RBF epilogue, rect-triangular tiles ----
// 128x256 block, 4 waves each computing a FULL-HEIGHT 128x64 strip (0.375
// ds_reads/MFMA vs 0.5 for 64x64 waves), BK=32, LDS 48KB dbuf -> 2 blocks/CU.
// R7's verified counted-vmcnt discipline: stage(t+1); vmcnt(6); barrier;
// compute(t); barrier. Per-128-col-half weight {0,1,2} handles the diagonal.
__global__ __launch_bounds__(256, 2) void mmd_gemm(const short* __restrict__ T,
                                                   const float* __restrict__ sq,
                                                   const float* __restrict__ bwp,
                                                   float* __restrict__ partials) {
  __shared__ __align__(16) short sA0[128 * 32], sA1[128 * 32];
  __shared__ __align__(16) short sB0[256 * 32], sB1[256 * 32];
  __shared__ float wred[4];

  const int tid  = threadIdx.x;
  const int lane = tid & 63;
  const int wave = tid >> 6;       // 0..3 = 64-col strip index
  const int wc   = wave;

  // XCD-aware chunked swizzle: 8 XCDs x 132 contiguous tiles (1056 = 8*132)
  const int tno = (blockIdx.x & 7) * 132 + (blockIdx.x >> 3);
  // pair-row decode: g(P) = P*(65-P); P=row-pair, then 2*(32-P) tiles inside
  int P = (int)((65.0f - fast_sqrt(65.f * 65.f - 4.f * (float)tno)) * 0.5f);
  while (P > 0 && P * (65 - P) > tno) --P;
  while ((P + 1) * (64 - P) <= tno) ++P;
  const int rem = tno - P * (65 - P);
  const int cnt = 32 - P;
  const int Bi  = 2 * P + (rem >= cnt ? 1 : 0);              // 128-row tile, 0..63
  const int Bjp = P + (rem >= cnt ? rem - cnt : rem);        // 256-col tile, 0..31

  const size_t arow = (size_t)Bi * 128;
  const size_t brow = (size_t)Bjp * 256;

  // staging source offsets (pre-swizzled; k0 added per tile)
  int goff[6];
#pragma unroll
  for (int l = 0; l < 2; ++l) {
    const int f = l * 256 + tid;
    const int sp = (f & 7) ^ ((f >> 3) & 7);
    goff[l] = (int)((arow + 2 * (f >> 3) + (sp >> 2)) * DIM) + (sp & 3) * 8;
  }
#pragma unroll
  for (int l = 0; l < 4; ++l) {
    const int f = l * 256 + tid;
    const int sp = (f & 7) ^ ((f >> 3) & 7);
    goff[2 + l] = (int)((brow + 2 * (f >> 3) + (sp >> 2)) * DIM) + (sp & 3) * 8;
  }

  const int r15 = lane & 15;
  const int kg  = lane >> 4;       // 0..3
  const int hi  = kg;

  // ds_read offsets (shorts), constant across tiles
  int aoffl[8], boffl[4];
#pragma unroll
  for (int m = 0; m < 8; ++m) {
    const int row = m * 16 + r15;
    aoffl[m] = ((row >> 1) * 8 + ((kg + 4 * (row & 1)) ^ ((row >> 1) & 7))) * 8;
  }
#pragma unroll
  for (int n = 0; n < 4; ++n) {
    const int row = wc * 64 + n * 16 + r15;
    boffl[n] = ((row >> 1) * 8 + ((kg + 4 * (row & 1)) ^ ((row >> 1) & 7))) * 8;
  }

  f32x4 acc[8][4] = {};

  // prologue: stage K-tile 0
  STAGE6(0, sA0, sB0);

  for (int t = 0; t < 16; ++t) {
    // even tile 2t in buf0; stage 2t+1 into buf1
    STAGE6((2 * t + 1) * 32, sA1, sB1);
    asm volatile("s_waitcnt vmcnt(6)" ::: "memory");   // tile-2t loads landed
    __builtin_amdgcn_s_barrier();
    __builtin_amdgcn_sched_barrier(0);
    COMPUTE32(sA0, sB0);
    __builtin_amdgcn_sched_barrier(0);
    __builtin_amdgcn_s_barrier();                      // buf0 reads done everywhere

    // odd tile 2t+1 in buf1; stage 2t+2 into buf0
    if (t < 15) {
      STAGE6((2 * t + 2) * 32, sA0, sB0);
      asm volatile("s_waitcnt vmcnt(6)" ::: "memory");
    } else {
      asm volatile("s_waitcnt vmcnt(0)" ::: "memory");
    }
    __builtin_amdgcn_s_barrier();
    __builtin_amdgcn_sched_barrier(0);
    COMPUTE32(sA1, sB1);
    __builtin_amdgcn_sched_barrier(0);
    __builtin_amdgcn_s_barrier();                      // buf1 reads done everywhere
  }

  // per-wave sign x weight: col-tile ct = 2*Bjp + (wc>>1) vs row-tile Bi
  const int ct = 2 * Bjp + (wc >> 1);
  float wsgn = (Bi < ct) ? 2.f : (Bi == ct ? 1.f : 0.f);
  if ((Bi < 32) != (ct < 32)) wsgn = -wsgn;

  // epilogue: x = l2*ni0 in exp2 domain; u = 2^(x/16);
  // sum_k exp2(x/2^k) = u + u^2 + u^4 + u^8 + u^16  (1 trans op total)
  const float s16 = bwp[0] * 0.0625f;  // -log2e/(16*bw)
  const float c2  = -2.f * s16;

  float ai[8][4];
#pragma unroll
  for (int m = 0; m < 8; ++m)
#pragma unroll
    for (int r = 0; r < 4; ++r)
      ai[m][r] = sq[Bi * 128 + m * 16 + hi * 4 + r] * s16;

  float tsum = 0.f;
#pragma unroll
  for (int n = 0; n < 4; ++n) {
    const float bjv = sq[Bjp * 256 + wc * 64 + n * 16 + r15] * s16;
#pragma unroll
    for (int m = 0; m < 8; ++m) {
#pragma unroll
      for (int r = 0; r < 4; ++r) {
        float x16 = fmaf(acc[m][n][r], c2, ai[m][r] + bjv);  // in [-0.9, 0]
        float u   = fast_exp2(x16);
        float u2 = u * u, u4 = u2 * u2, u8 = u4 * u4, u16 = u8 * u8;
        tsum += ((u + u2) + (u4 + u8)) + u16;
      }
    }
  }
  tsum *= wsgn;

#pragma unroll
  for (int off = 32; off > 0; off >>= 1) tsum += __shfl_down(tsum, off, 64);
  if (lane == 0) wred[wave] = tsum;
  __syncthreads();
  if (tid == 0)
    partials[tno] = (wred[0] + wred[1]) + (wred[2] + wred[3]);
}

// ---- kernel E: final reduction ----
__global__ __launch_bounds__(256) void finish_kernel(const float* __restrict__ partials,
                                                     float* __restrict__ out) {
  const int t = threadIdx.x;
  double s = 0.0;
  for (int i = t; i < NT2; i += 256) s += (double)partials[i];
  __shared__ double rd[256];
  rd[t] = s;
  __syncthreads();
  for (int off = 128; off > 0; off >>= 1) {
    if (t < off) rd[t] += rd[t + off];
    __syncthreads();
  }
  if (t == 0) out[0] = (float)(rd[0] / 16777216.0);  // / bs^2
}

extern "C" void kernel_launch(void* const* d_in, const int* in_sizes, int n_in,
                              void* d_out, int out_size, void* d_ws, size_t ws_size,
                              hipStream_t stream) {
  const float* src = (const float*)d_in[0];
  const float* tgt = (const float*)d_in[1];
  char* ws = (char*)d_ws;
  unsigned short* tb = (unsigned short*)(ws + OFF_TB);
  float* sq       = (float*)(ws + OFF_SQ);
  float* colpart  = (float*)(ws + OFF_COLPART);
  float* bwp      = (float*)(ws + OFF_BWP);
  float* partials = (float*)(ws + OFF_PART);

  prep_kernel<<<dim3(512), dim3(256), 0, stream>>>(src, tgt, tb, sq);
  colsum_kernel<<<dim3(128), dim3(256), 0, stream>>>(tb, colpart);
  bw_kernel<<<dim3(1), dim3(1024), 0, stream>>>(sq, colpart, bwp);
  mmd_gemm<<<dim3(NT2), dim3(256), 0, stream>>>((const short*)tb, sq, bwp, partials);
  finish_kernel<<<dim3(1), dim3(256), 0, stream>>>(partials, (float*)d_out);
}